// Round 1
// baseline (842.597 us; speedup 1.0000x reference)
//
#include <hip/hip_runtime.h>

#define N_NODES 100000
#define IN_F    256
#define OUT_F   256
#define BATCH   50000
#define NSAMP   25
#define K2      (2 * IN_F)   // 512
#define BM      16           // batch rows per block; 50000 = 16 * 3125 exactly

// Fused SAGE layer: gather self + mean(25 neighbors) -> LDS, then
// out[16 x 256] = comb[16 x 512] @ W[256 x 512]^T  (fp32 vector FMA).
__global__ __launch_bounds__(256, 4) void sage_fused(
    const float* __restrict__ features,   // [N_NODES][IN_F]
    const int*   __restrict__ node_idx,   // [BATCH]
    const int*   __restrict__ neigh_idx,  // [BATCH][NSAMP]
    const float* __restrict__ W,          // [OUT_F][K2] row-major
    float*       __restrict__ out)        // [BATCH][OUT_F]
{
    __shared__ float comb[BM][K2];        // 32 KB

    const int tid  = threadIdx.x;
    const int lane = tid & 63;
    const int wy   = tid >> 6;            // wave id 0..3
    const int b0   = blockIdx.x * BM;

    // ---------------- Phase A: gather + mean into LDS ----------------
    // Each wave handles 4 rows; each lane owns 4 consecutive feature cols.
    #pragma unroll
    for (int i = 0; i < 4; ++i) {
        const int r = wy * 4 + i;
        const int b = b0 + r;

        const int self_n = node_idx[b];
        const float4 sf = *(const float4*)&features[(long)self_n * IN_F + lane * 4];
        *(float4*)&comb[r][lane * 4] = sf;

        float4 acc = make_float4(0.f, 0.f, 0.f, 0.f);
        for (int s = 0; s < NSAMP; ++s) {
            const int nn = neigh_idx[b * NSAMP + s];
            const float4 nf = *(const float4*)&features[(long)nn * IN_F + lane * 4];
            acc.x += nf.x; acc.y += nf.y; acc.z += nf.z; acc.w += nf.w;
        }
        const float inv = 1.0f / (float)NSAMP;
        acc.x *= inv; acc.y *= inv; acc.z *= inv; acc.w *= inv;
        *(float4*)&comb[r][IN_F + lane * 4] = acc;
    }
    __syncthreads();

    // ---------------- Phase B: fp32 GEMM tile ----------------
    // Thread tile: 4 rows (wy*4 .. wy*4+3) x 4 cols (lane*4 .. lane*4+3).
    // comb reads are wave-uniform-address ds_read_b128 (broadcast, no conflicts).
    const int c0 = lane * 4;
    float acc[4][4] = {};

    for (int k0 = 0; k0 < K2; k0 += 4) {
        float4 a4[4];
        float4 w4[4];
        #pragma unroll
        for (int i = 0; i < 4; ++i)
            a4[i] = *(const float4*)&comb[wy * 4 + i][k0];
        #pragma unroll
        for (int j = 0; j < 4; ++j)
            w4[j] = *(const float4*)&W[(long)(c0 + j) * K2 + k0];
        #pragma unroll
        for (int i = 0; i < 4; ++i) {
            #pragma unroll
            for (int j = 0; j < 4; ++j) {
                acc[i][j] += a4[i].x * w4[j].x + a4[i].y * w4[j].y
                           + a4[i].z * w4[j].z + a4[i].w * w4[j].w;
            }
        }
    }

    #pragma unroll
    for (int i = 0; i < 4; ++i) {
        const int b = b0 + wy * 4 + i;
        float4 o4 = make_float4(acc[i][0], acc[i][1], acc[i][2], acc[i][3]);
        *(float4*)&out[(long)b * OUT_F + c0] = o4;
    }
}

extern "C" void kernel_launch(void* const* d_in, const int* in_sizes, int n_in,
                              void* d_out, int out_size, void* d_ws, size_t ws_size,
                              hipStream_t stream) {
    const float* features  = (const float*)d_in[0];
    const int*   node_idx  = (const int*)d_in[1];
    const int*   neigh_idx = (const int*)d_in[2];
    const float* W         = (const float*)d_in[3];
    float*       out       = (float*)d_out;

    const int grid = BATCH / BM;  // 3125
    sage_fused<<<grid, 256, 0, stream>>>(features, node_idx, neigh_idx, W, out);
}

// Round 2
// 309.973 us; speedup vs baseline: 2.7183x; 2.7183x over previous
//
#include <hip/hip_runtime.h>

#define N_NODES 100000
#define IN_F    256
#define OUT_F   256
#define BATCH   50000
#define NSAMP   25
#define K2      512          // 2*IN_F
#define BM      16           // batch rows per block; 50000 = 16 * 3125

typedef __bf16 bf16_t;
typedef bf16_t bf16x8 __attribute__((ext_vector_type(8)));
typedef float  f32x4  __attribute__((ext_vector_type(4)));

// LDS is logically comb[BM][K2] in bf16 (row stride 1024 B). Without swizzle,
// phase-B A-fragment reads (16 lanes -> 16 rows, same 16B k-slot) are a
// 16-way bank conflict. XOR byte bits 4..6 with (row&7): ushort-index bits 3..5.
__device__ __forceinline__ int swz(int row, int us_idx) {
    return us_idx ^ ((row & 7) << 3);
}

__device__ __forceinline__ void store_bf4(unsigned short* comb, int r, int col, float4 f) {
    union { ushort4 u; bf16_t b[4]; } t;
    t.b[0] = (bf16_t)f.x; t.b[1] = (bf16_t)f.y;
    t.b[2] = (bf16_t)f.z; t.b[3] = (bf16_t)f.w;
    *(ushort4*)&comb[swz(r, r * K2 + col)] = t.u;   // 8B chunk stays inside a 16B block
}

__global__ __launch_bounds__(256, 4) void sage_fused(
    const float* __restrict__ features,   // [N_NODES][IN_F] fp32
    const int*   __restrict__ node_idx,   // [BATCH]
    const int*   __restrict__ neigh_idx,  // [BATCH][NSAMP]
    const float* __restrict__ W,          // [OUT_F][K2] fp32 row-major
    float*       __restrict__ out)        // [BATCH][OUT_F] fp32
{
    __shared__ unsigned short comb[BM * K2];   // bf16 bits, swizzled, 16 KB

    const int tid  = threadIdx.x;
    const int lane = tid & 63;
    const int wy   = tid >> 6;            // wave 0..3
    const int b0   = blockIdx.x * BM;
    const int col4 = lane * 4;            // each lane owns 4 consecutive feature cols

    // ---------------- Phase A: gather + mean -> bf16 LDS ----------------
    #pragma unroll
    for (int i = 0; i < 4; ++i) {
        const int r = wy * 4 + i;
        const long b = b0 + r;

        // wave-uniform index loads (compiler scalarizes -> SGPRs, issued early)
        int nidx[NSAMP];
        #pragma unroll
        for (int s = 0; s < NSAMP; ++s) nidx[s] = neigh_idx[b * NSAMP + s];
        const int self_n = node_idx[b];

        const float4 sf = *(const float4*)&features[(long)self_n * IN_F + col4];

        // batch 13 + 12 loads so ~13 gathered 1KB loads stay in flight per wave
        float4 v[13];
        #pragma unroll
        for (int s = 0; s < 13; ++s)
            v[s] = *(const float4*)&features[(long)nidx[s] * IN_F + col4];
        float4 acc = v[0];
        #pragma unroll
        for (int s = 1; s < 13; ++s) {
            acc.x += v[s].x; acc.y += v[s].y; acc.z += v[s].z; acc.w += v[s].w;
        }
        #pragma unroll
        for (int s = 13; s < NSAMP; ++s)
            v[s - 13] = *(const float4*)&features[(long)nidx[s] * IN_F + col4];
        #pragma unroll
        for (int s = 0; s < 12; ++s) {
            acc.x += v[s].x; acc.y += v[s].y; acc.z += v[s].z; acc.w += v[s].w;
        }
        const float inv = 1.0f / (float)NSAMP;
        acc.x *= inv; acc.y *= inv; acc.z *= inv; acc.w *= inv;

        store_bf4(comb, r, col4, sf);          // self   -> cols [0,256)
        store_bf4(comb, r, IN_F + col4, acc);  // mean   -> cols [256,512)
    }
    __syncthreads();

    // ---------------- Phase B: bf16 MFMA, out tile 16 x 256 ----------------
    // Wave wy owns output cols [wy*64, wy*64+64) as 4 tiles of 16x16, K=512.
    // mfma_f32_16x16x32_bf16: A lane l -> A[l&15][8*(l>>4)+j]; B lane l ->
    // B[8*(l>>4)+j][l&15]; D lane l reg j -> D[(l>>4)*4+j][l&15].
    const int c0   = wy * 64;
    const int arow = lane & 15;
    const int kq   = (lane >> 4) * 8;

    f32x4 acc[4];
    #pragma unroll
    for (int t = 0; t < 4; ++t) acc[t] = (f32x4){0.f, 0.f, 0.f, 0.f};

    #pragma unroll
    for (int ks = 0; ks < 16; ++ks) {
        const int kb = ks * 32 + kq;
        const bf16x8 af = *(const bf16x8*)&comb[swz(arow, arow * K2 + kb)];
        #pragma unroll
        for (int t = 0; t < 4; ++t) {
            const float* wp = &W[(long)(c0 + t * 16 + arow) * K2 + kb];
            const float4 w0 = *(const float4*)wp;
            const float4 w1 = *(const float4*)(wp + 4);
            bf16x8 bf;
            bf[0] = (bf16_t)w0.x; bf[1] = (bf16_t)w0.y;
            bf[2] = (bf16_t)w0.z; bf[3] = (bf16_t)w0.w;
            bf[4] = (bf16_t)w1.x; bf[5] = (bf16_t)w1.y;
            bf[6] = (bf16_t)w1.z; bf[7] = (bf16_t)w1.w;
            acc[t] = __builtin_amdgcn_mfma_f32_16x16x32_bf16(af, bf, acc[t], 0, 0, 0);
        }
    }

    #pragma unroll
    for (int t = 0; t < 4; ++t) {
        const int col = c0 + t * 16 + arow;
        #pragma unroll
        for (int j = 0; j < 4; ++j) {
            const int row = b0 + (lane >> 4) * 4 + j;
            out[(long)row * OUT_F + col] = acc[t][j];
        }
    }
}

extern "C" void kernel_launch(void* const* d_in, const int* in_sizes, int n_in,
                              void* d_out, int out_size, void* d_ws, size_t ws_size,
                              hipStream_t stream) {
    const float* features  = (const float*)d_in[0];
    const int*   node_idx  = (const int*)d_in[1];
    const int*   neigh_idx = (const int*)d_in[2];
    const float* W         = (const float*)d_in[3];
    float*       out       = (float*)d_out;

    sage_fused<<<BATCH / BM, 256, 0, stream>>>(features, node_idx, neigh_idx, W, out);
}

// Round 3
// 200.231 us; speedup vs baseline: 4.2081x; 1.5481x over previous
//
#include <hip/hip_runtime.h>

#define N_NODES 100000
#define IN_F    256
#define OUT_F   256
#define BATCH   50000
#define NSAMP   25
#define K2      512

typedef _Float16 f16_t;
typedef f16_t f16x8 __attribute__((ext_vector_type(8)));
typedef float f32x4 __attribute__((ext_vector_type(4)));
typedef __bf16 bf16_t;
typedef bf16_t bf16x8 __attribute__((ext_vector_type(8)));

// workspace layout (bytes)
#define PNEIGH_OFF 51200000L                 // 100000*256*2
#define WG_OFF     102400000L
#define WS_NEED    (WG_OFF + 512L * 256 * 2) // 102,662,144

__device__ __forceinline__ float h2f(unsigned short u) {
    union { unsigned short u; f16_t h; } t; t.u = u; return (float)t.h;
}

// ---------------- Kernel 0: rearrange W -> Wg[512][256] f16 ----------------
// Wg[j][k] = W[j][k] (j<256, self half) ; W[j-256][256+k] (neigh half)
__global__ void wconv(const float* __restrict__ W, f16_t* __restrict__ Wg) {
    int idx = blockIdx.x * 256 + threadIdx.x;   // 0..131071
    int j = idx >> 8, k = idx & 255;
    float v = (j < 256) ? W[j * K2 + k] : W[(j - 256) * K2 + 256 + k];
    Wg[idx] = (f16_t)v;
}

// ---------------- Kernel 1: P = F @ Wg^T  (f16 MFMA) ----------------
// Block: 64 feature rows x all 512 P-cols. Operands SWAPPED in the MFMA
// (A-op = Wg, B-op = features) so each lane's D regs hold 4 CONSECUTIVE
// P-cols of one row -> 8B packed f16 stores.
__global__ __launch_bounds__(256, 2) void proj_gemm(
    const float* __restrict__ features, const f16_t* __restrict__ Wg,
    f16_t* __restrict__ Pself, f16_t* __restrict__ Pneigh)
{
    __shared__ unsigned short atile[64 * 256];  // f16 bits, XOR-swizzled, 32 KB
    const int tid = threadIdx.x, lane = tid & 63, w = tid >> 6;
    const long gr0 = (long)blockIdx.x * 64;

    // stage 64x256 fp32 -> f16 LDS (swizzle: us_idx ^= (row&7)<<3, 16B blocks)
    #pragma unroll
    for (int i = 0; i < 16; ++i) {
        int q = tid + i * 256;                  // float4 id 0..4095
        int row = q >> 6, c4 = (q & 63) * 4;
        long srow = gr0 + row; if (srow > N_NODES - 1) srow = N_NODES - 1;
        float4 f = *(const float4*)&features[srow * IN_F + c4];
        union { ushort4 u; f16_t h[4]; } t;
        t.h[0] = (f16_t)f.x; t.h[1] = (f16_t)f.y;
        t.h[2] = (f16_t)f.z; t.h[3] = (f16_t)f.w;
        *(ushort4*)&atile[(row * 256 + c4) ^ ((row & 7) << 3)] = t.u;
    }
    __syncthreads();

    const int c0 = w * 128;                     // this wave's 128 P-cols
    const int q16 = lane >> 4, r16 = lane & 15;

    f32x4 acc[8][4];
    #pragma unroll
    for (int ct = 0; ct < 8; ++ct)
        #pragma unroll
        for (int rt = 0; rt < 4; ++rt) acc[ct][rt] = (f32x4){0.f, 0.f, 0.f, 0.f};

    #pragma unroll
    for (int s = 0; s < 8; ++s) {
        const int kb = s * 32 + q16 * 8;
        f16x8 bfr[4];                           // B-op: feature rows from LDS
        #pragma unroll
        for (int rt = 0; rt < 4; ++rt) {
            int row = rt * 16 + r16;
            bfr[rt] = *(const f16x8*)&atile[(row * 256 + kb) ^ ((row & 7) << 3)];
        }
        #pragma unroll
        for (int ct = 0; ct < 8; ++ct) {
            const f16x8 afr = *(const f16x8*)&Wg[(long)(c0 + ct * 16 + r16) * 256 + kb];
            #pragma unroll
            for (int rt = 0; rt < 4; ++rt)
                acc[ct][rt] = __builtin_amdgcn_mfma_f32_16x16x32_f16(afr, bfr[rt], acc[ct][rt], 0, 0, 0);
        }
    }

    // D[m][n]: m = P-col-in-tile = q16*4+j, n = row-in-tile = r16
    #pragma unroll
    for (int ct = 0; ct < 8; ++ct) {
        const int colb = c0 + ct * 16 + q16 * 4;        // 4 consecutive P cols
        #pragma unroll
        for (int rt = 0; rt < 4; ++rt) {
            const long row = gr0 + rt * 16 + r16;
            if (row < N_NODES) {
                union { ushort4 u; f16_t h[4]; } t;
                t.h[0] = (f16_t)acc[ct][rt][0]; t.h[1] = (f16_t)acc[ct][rt][1];
                t.h[2] = (f16_t)acc[ct][rt][2]; t.h[3] = (f16_t)acc[ct][rt][3];
                f16_t* dst = (colb < 256) ? (Pself + row * 256 + colb)
                                          : (Pneigh + row * 256 + (colb - 256));
                *(ushort4*)dst = t.u;
            }
        }
    }
}

// ---------------- Kernel 2: out[b] = Pself[ni[b]] + mean_s Pneigh[nb[b,s]] ----------------
__global__ __launch_bounds__(256) void gather_add(
    const f16_t* __restrict__ Pself, const f16_t* __restrict__ Pneigh,
    const int* __restrict__ node_idx, const int* __restrict__ neigh_idx,
    float* __restrict__ out)
{
    const int tid = threadIdx.x, lane = tid & 63, w = tid >> 6;
    const long b = (long)blockIdx.x * 4 + w;    // one row per wave
    const int c4 = lane * 4;                    // 4 f16 per lane (8B)

    int ns[NSAMP];
    #pragma unroll
    for (int s = 0; s < NSAMP; ++s) ns[s] = neigh_idx[b * NSAMP + s];
    const int self_n = node_idx[b];

    const ushort4 sv = *(const ushort4*)&Pself[(long)self_n * 256 + c4];

    float4 a = make_float4(0.f, 0.f, 0.f, 0.f);
    ushort4 v[13];
    #pragma unroll
    for (int s = 0; s < 13; ++s)
        v[s] = *(const ushort4*)&Pneigh[(long)ns[s] * 256 + c4];
    #pragma unroll
    for (int s = 0; s < 13; ++s) {
        a.x += h2f(v[s].x); a.y += h2f(v[s].y);
        a.z += h2f(v[s].z); a.w += h2f(v[s].w);
    }
    #pragma unroll
    for (int s = 13; s < NSAMP; ++s)
        v[s - 13] = *(const ushort4*)&Pneigh[(long)ns[s] * 256 + c4];
    #pragma unroll
    for (int s = 0; s < 12; ++s) {
        a.x += h2f(v[s].x); a.y += h2f(v[s].y);
        a.z += h2f(v[s].z); a.w += h2f(v[s].w);
    }

    const float inv = 1.0f / (float)NSAMP;
    float4 o;
    o.x = h2f(sv.x) + a.x * inv;
    o.y = h2f(sv.y) + a.y * inv;
    o.z = h2f(sv.z) + a.z * inv;
    o.w = h2f(sv.w) + a.w * inv;
    *(float4*)&out[b * OUT_F + c4] = o;
}

// ---------------- Fallback (R2 monolithic) if ws too small ----------------
__device__ __forceinline__ int swz_bf(int row, int us_idx) {
    return us_idx ^ ((row & 7) << 3);
}
__device__ __forceinline__ void store_bf4(unsigned short* comb, int r, int col, float4 f) {
    union { ushort4 u; bf16_t b[4]; } t;
    t.b[0] = (bf16_t)f.x; t.b[1] = (bf16_t)f.y;
    t.b[2] = (bf16_t)f.z; t.b[3] = (bf16_t)f.w;
    *(ushort4*)&comb[swz_bf(r, r * K2 + col)] = t.u;
}
__global__ __launch_bounds__(256, 4) void sage_fused(
    const float* __restrict__ features, const int* __restrict__ node_idx,
    const int* __restrict__ neigh_idx, const float* __restrict__ W,
    float* __restrict__ out)
{
    __shared__ unsigned short comb[16 * K2];
    const int tid = threadIdx.x, lane = tid & 63, wy = tid >> 6;
    const int b0 = blockIdx.x * 16;
    const int col4 = lane * 4;
    #pragma unroll
    for (int i = 0; i < 4; ++i) {
        const int r = wy * 4 + i;
        const long b = b0 + r;
        int nidx[NSAMP];
        #pragma unroll
        for (int s = 0; s < NSAMP; ++s) nidx[s] = neigh_idx[b * NSAMP + s];
        const int self_n = node_idx[b];
        const float4 sf = *(const float4*)&features[(long)self_n * IN_F + col4];
        float4 v[13];
        #pragma unroll
        for (int s = 0; s < 13; ++s)
            v[s] = *(const float4*)&features[(long)nidx[s] * IN_F + col4];
        float4 acc = v[0];
        #pragma unroll
        for (int s = 1; s < 13; ++s) {
            acc.x += v[s].x; acc.y += v[s].y; acc.z += v[s].z; acc.w += v[s].w;
        }
        #pragma unroll
        for (int s = 13; s < NSAMP; ++s)
            v[s - 13] = *(const float4*)&features[(long)nidx[s] * IN_F + col4];
        #pragma unroll
        for (int s = 0; s < 12; ++s) {
            acc.x += v[s].x; acc.y += v[s].y; acc.z += v[s].z; acc.w += v[s].w;
        }
        const float inv = 1.0f / (float)NSAMP;
        acc.x *= inv; acc.y *= inv; acc.z *= inv; acc.w *= inv;
        store_bf4(comb, r, col4, sf);
        store_bf4(comb, r, IN_F + col4, acc);
    }
    __syncthreads();
    const int c0 = wy * 64, arow = lane & 15, kq = (lane >> 4) * 8;
    f32x4 acc[4];
    #pragma unroll
    for (int t = 0; t < 4; ++t) acc[t] = (f32x4){0.f, 0.f, 0.f, 0.f};
    #pragma unroll
    for (int ks = 0; ks < 16; ++ks) {
        const int kb = ks * 32 + kq;
        const bf16x8 af = *(const bf16x8*)&comb[swz_bf(arow, arow * K2 + kb)];
        #pragma unroll
        for (int t = 0; t < 4; ++t) {
            const float* wp = &W[(long)(c0 + t * 16 + arow) * K2 + kb];
            const float4 w0 = *(const float4*)wp;
            const float4 w1 = *(const float4*)(wp + 4);
            bf16x8 bf;
            bf[0] = (bf16_t)w0.x; bf[1] = (bf16_t)w0.y;
            bf[2] = (bf16_t)w0.z; bf[3] = (bf16_t)w0.w;
            bf[4] = (bf16_t)w1.x; bf[5] = (bf16_t)w1.y;
            bf[6] = (bf16_t)w1.z; bf[7] = (bf16_t)w1.w;
            acc[t] = __builtin_amdgcn_mfma_f32_16x16x32_bf16(af, bf, acc[t], 0, 0, 0);
        }
    }
    #pragma unroll
    for (int t = 0; t < 4; ++t) {
        const int col = c0 + t * 16 + arow;
        #pragma unroll
        for (int j = 0; j < 4; ++j) {
            const int row = b0 + (lane >> 4) * 4 + j;
            out[(long)row * OUT_F + col] = acc[t][j];
        }
    }
}

extern "C" void kernel_launch(void* const* d_in, const int* in_sizes, int n_in,
                              void* d_out, int out_size, void* d_ws, size_t ws_size,
                              hipStream_t stream) {
    const float* features  = (const float*)d_in[0];
    const int*   node_idx  = (const int*)d_in[1];
    const int*   neigh_idx = (const int*)d_in[2];
    const float* W         = (const float*)d_in[3];
    float*       out       = (float*)d_out;

    if (ws_size >= (size_t)WS_NEED) {
        f16_t* Pself  = (f16_t*)d_ws;
        f16_t* Pneigh = (f16_t*)((char*)d_ws + PNEIGH_OFF);
        f16_t* Wg     = (f16_t*)((char*)d_ws + WG_OFF);
        wconv<<<512, 256, 0, stream>>>(W, Wg);
        proj_gemm<<<1563, 256, 0, stream>>>(features, Wg, Pself, Pneigh);
        gather_add<<<BATCH / 4, 256, 0, stream>>>(Pself, Pneigh, node_idx, neigh_idx, out);
    } else {
        sage_fused<<<BATCH / 16, 256, 0, stream>>>(features, node_idx, neigh_idx, W, out);
    }
}